// Round 10
// baseline (247.815 us; speedup 1.0000x reference)
//
#include <hip/hip_runtime.h>
#include <hip/hip_fp16.h>

// ADI diffusion B=16, C=8, S=128, 10 steps. Round 19: single persistent
// kernel, point-to-point neighbor sync (no grid barrier, no threadfence).
// u band lives in LDS all 10 steps; per step each block publishes its 4
// edge rows via relaxed AGENT-scope atomic stores (coherence-point = MALL,
// cross-XCD safe, no wbl2) + a flag after __syncthreads (drains vmcnt).
// Readers spin on 2 neighbor flags, atomic-load 4 halo rows. Double-
// buffered halo slots; lead<=1 step provable => race-free; 256 co-resident
// blocks (proven r4/r5) + line-DAG waits => deadlock-free.
// Coeffs packed __half2{g, rb-1} precomputed in one small dispatch (r9).

constexpr int S_  = 128;
constexpr int RS  = 129;            // padded LDS row stride
constexpr float EPSF = 1e-6f;
constexpr int CSS  = 8 * 128 * 128; // points per coeff field
constexpr int NBLK = 256;

// LDS rows (RS floats each):
//  U [0,64)    persistent u band (r = c*8+ho)
//  A [64,128)  Y-out / mix-out
//  B [128,192) x1 park
//  C [192,256) packed x-coeff (stored as float-bits)
//  head reuse: ST 96 rows at [64,160); x@0 halo rows 32 at [160,192)
constexpr int OFF_U  = 0;
constexpr int OFF_A  = 64 * RS;
constexpr int OFF_B  = 128 * RS;
constexpr int OFF_C  = 192 * RS;
constexpr int OFF_ST = 64 * RS;
constexpr int OFF_HB = 160 * RS;
constexpr int POOL   = 256 * RS;    // 132096 B

template <int N>
__device__ __forceinline__ void jrunN(const float (&e)[N], const float (&g)[N],
                                      float (&o)[N - 4]) {
    // Jacobi-2 == fixed 5-point formula, stencil radius 2 per output.
    float x1[N];
    #pragma unroll
    for (int i = 1; i <= N - 2; ++i) x1[i] = fmaf(g[i], e[i - 1] + e[i + 1], e[i]);
    #pragma unroll
    for (int i = 2; i <= N - 3; ++i) o[i - 2] = fmaf(g[i], x1[i - 1] + x1[i + 1], e[i]);
}

// ---- coefficient precompute (round-9, proven): fields 0..9 Y@t_y(k),
// 10..19 X@t_x(k), 20 X@t=0. Packed __half2{g = rb*co, rb-1}.
__global__ __launch_bounds__(256) void coef_kernel(
    const float* __restrict__ ab, const float* __restrict__ atc,
    const float* __restrict__ bb, const float* __restrict__ btc,
    __half2* __restrict__ cf)
{
    for (int gc = blockIdx.x * 256 + threadIdx.x; gc < CSS; gc += gridDim.x * 256) {
        const int w = gc & 127, h = (gc >> 7) & 127;
        const float abv = ab[gc], atv = atc[gc], bbv = bb[gc], btv = btc[gc];
        const float nbY = (h == 0 || h == S_ - 1) ? 1.f : 2.f;
        const float nbX = (w == 0 || w == S_ - 1) ? 1.f : 2.f;
        for (int k = 0; k < 10; ++k) {
            const float ty = (2 * k + 1) * 0.0005f;
            const float tx = (2 * k + 2) * 0.0005f;
            float be = fminf(fmaxf(fmaf(btv, ty, bbv), EPSF), 10.f);
            float co = be * 0.001f;
            float rb = __builtin_amdgcn_rcpf(fmaf(nbY, co, 1.f) + EPSF);
            cf[k * CSS + gc] = __floats2half2_rn(rb * co, rb - 1.f);
            float al = fminf(fmaxf(fmaf(atv, tx, abv), EPSF), 10.f);
            co = al * 0.0005f;
            rb = __builtin_amdgcn_rcpf(fmaf(nbX, co, 1.f) + EPSF);
            cf[(10 + k) * CSS + gc] = __floats2half2_rn(rb * co, rb - 1.f);
        }
        float al = fminf(fmaxf(abv, EPSF), 10.f);
        float co = al * 0.0005f;
        float rb = __builtin_amdgcn_rcpf(fmaf(nbX, co, 1.f) + EPSF);
        cf[20 * CSS + gc] = __floats2half2_rn(rb * co, rb - 1.f);
    }
}

__global__ __launch_bounds__(512, 2) void adi10_kernel(
    const float* __restrict__ u0, float* __restrict__ uout,
    const __half2* __restrict__ cf, const float* __restrict__ cm,
    float* __restrict__ halo, unsigned* __restrict__ flags)
{
    __shared__ float sP[POOL];
    const int tid   = threadIdx.x;
    const int blk   = blockIdx.x;
    const int b     = blk >> 4;
    const int chunk = blk & 15;
    const int h0    = chunk << 3;

    // ==== head: stage 12-row pristine tile -> mix -> x@0 into U + HB ====
    #pragma unroll
    for (int m = 0; m < 2; ++m) {
        const int col = tid + 512 * m;
        const int c = col >> 7, w = col & 127;
        #pragma unroll
        for (int hh = 0; hh < 12; ++hh) {
            const int gh = h0 - 2 + hh;
            float v = 0.f;
            if (gh >= 0 && gh < S_) v = u0[((b * 8 + c) * S_ + gh) * S_ + w];
            sP[OFF_ST + (c * 12 + hh) * RS + w] = v;
        }
    }
    __syncthreads();
    {   // channel mix in place on ST (1536 points, 3/thread)
        float M[64];
        #pragma unroll
        for (int i = 0; i < 64; ++i) M[i] = cm[i];
        #pragma unroll
        for (int m = 0; m < 3; ++m) {
            const int p = tid + 512 * m;
            const int hh = p >> 7, w = p & 127;
            float v[8], o[8];
            #pragma unroll
            for (int c = 0; c < 8; ++c) v[c] = sP[OFF_ST + (c * 12 + hh) * RS + w];
            #pragma unroll
            for (int dd = 0; dd < 8; ++dd) {
                float a = 0.f;
                #pragma unroll
                for (int c = 0; c < 8; ++c) a = fmaf(M[dd * 8 + c], v[c], a);
                o[dd] = a;
            }
            #pragma unroll
            for (int c = 0; c < 8; ++c) sP[OFF_ST + (c * 12 + hh) * RS + w] = o[c];
        }
    }
    __syncthreads();
    {   // x@0: 96 rows x 16 runs, 3/thread; packed cfx0 per-tap (contig runs)
        const __half2* cfx0 = cf + 20 * CSS;
        #pragma unroll
        for (int m = 0; m < 3; ++m) {
            const int task = tid + 512 * m;
            const int r96 = task % 96, wr = task / 96;
            const int c = r96 / 12, hh = r96 % 12;
            const int gh = h0 - 2 + hh;
            const bool rowin = (gh >= 0 && gh < S_);
            const int ghc = rowin ? gh : 0;
            const int w0 = wr * 8;
            float e[12], g[12];
            #pragma unroll
            for (int j = 0; j < 12; ++j) {
                const int wj = w0 - 2 + j;
                const bool win = (wj >= 0 && wj < S_);
                const float dv = win ? sP[OFF_ST + r96 * RS + wj] : 0.f;
                float2 f = make_float2(0.f, 0.f);
                if (rowin && win) f = __half22float2(cfx0[(c * S_ + ghc) * S_ + wj]);
                e[j] = (1.f + f.y) * dv;
                g[j] = f.x;
            }
            float o[8]; jrunN<12>(e, g, o);
            const int urow = (hh >= 2 && hh < 10)
                ? OFF_U + (c * 8 + hh - 2) * RS
                : OFF_HB + (c * 4 + (hh < 2 ? hh : hh - 8)) * RS;
            #pragma unroll
            for (int i = 0; i < 8; ++i) sP[urow + w0 + i] = o[i];
        }
    }
    __syncthreads();

    // ==== 10 fused steps ====
    for (int k = 0; k < 10; ++k) {
        const __half2* cfy  = cf + k * CSS;
        const __half2* cfxk = cf + (10 + k) * CSS;

        if (k > 0) {    // wait for neighbors' step-(k-1) halos
            if (tid == 0 && chunk > 0)
                while (__hip_atomic_load(&flags[blk - 1], __ATOMIC_RELAXED,
                                         __HIP_MEMORY_SCOPE_AGENT) < (unsigned)k)
                    __builtin_amdgcn_s_sleep(2);
            if (tid == 1 && chunk < 15)
                while (__hip_atomic_load(&flags[blk + 1], __ATOMIC_RELAXED,
                                         __HIP_MEMORY_SCOPE_AGENT) < (unsigned)k)
                    __builtin_amdgcn_s_sleep(2);
            __syncthreads();
        }

        // ---- Y: 1024 (c,w) cols, 2/thread; 12-in -> 8-out -> A
        const int rslot = (k - 1) & 1;
        #pragma unroll
        for (int m = 0; m < 2; ++m) {
            const int col = tid + 512 * m;
            const int c = col >> 7, w = col & 127;
            float e[12], g[12];
            #pragma unroll
            for (int hh = 0; hh < 12; ++hh) {
                const int gh = h0 - 2 + hh;
                const bool inr = (gh >= 0 && gh < S_);
                const int ghc = inr ? gh : 0;
                float dv;
                if (hh >= 2 && hh < 10) {
                    dv = sP[OFF_U + (c * 8 + hh - 2) * RS + w];
                } else if (k == 0) {
                    dv = sP[OFF_HB + (c * 4 + (hh < 2 ? hh : hh - 8)) * RS + w];
                } else if (!inr) {
                    dv = 0.f;
                } else {
                    const int nb_ = (hh < 2) ? blk - 1 : blk + 1;
                    const int e_  = (hh < 2) ? 2 + hh : hh - 10;
                    dv = __hip_atomic_load(
                        &halo[(rslot * NBLK + nb_) * 4096 + (e_ * 8 + c) * 128 + w],
                        __ATOMIC_RELAXED, __HIP_MEMORY_SCOPE_AGENT);
                }
                const float2 f = __half22float2(cfy[(c * S_ + ghc) * S_ + w]);
                e[hh] = (1.f + f.y) * dv;
                g[hh] = inr ? f.x : 0.f;
            }
            float o[8]; jrunN<12>(e, g, o);
            #pragma unroll
            for (int i = 0; i < 8; ++i) sP[OFF_A + (c * 8 + i) * RS + w] = o[i];
        }
        // stage packed x-coeff into C (64 rows, uint2-coalesced)
        #pragma unroll
        for (int m = 0; m < 8; ++m) {
            const int task = tid + 512 * m;
            const int r = task >> 6, col2 = task & 63;
            const int c = r >> 3, ho = r & 7;
            const uint2 v = ((const uint2*)cfxk)[(c * S_ + h0 + ho) * 64 + col2];
            sP[OFF_C + r * RS + col2 * 2]     = __uint_as_float(v.x);
            sP[OFF_C + r * RS + col2 * 2 + 1] = __uint_as_float(v.y);
        }
        __syncthreads();

        // ---- X1: 64 rows x 16 runs, 2/thread; cache rb/g for X2
        float rbk[2][12], gk[2][12], xo[2][8];
        #pragma unroll
        for (int m = 0; m < 2; ++m) {
            const int run = tid + 512 * m;
            const int r = run & 63, wr = run >> 6;
            const int w0 = wr * 8;
            float e[12];
            #pragma unroll
            for (int j = 0; j < 12; ++j) {
                const int wj = w0 - 2 + j;
                const bool win = (wj >= 0 && wj < S_);
                const float dv = win ? sP[OFF_A + r * RS + wj] : 0.f;
                uint cb = win ? __float_as_uint(sP[OFF_C + r * RS + wj]) : 0u;
                const float2 f = __half22float2(*reinterpret_cast<__half2*>(&cb));
                rbk[m][j] = 1.f + f.y; gk[m][j] = f.x;
                e[j] = rbk[m][j] * dv;
            }
            jrunN<12>(e, gk[m], xo[m]);
        }

        if (k == 9) {   // final: no mix; xo -> fp32 d_out
            #pragma unroll
            for (int m = 0; m < 2; ++m) {
                const int run = tid + 512 * m;
                const int r = run & 63, wr = run >> 6;
                const int c = r >> 3, ho = r & 7;
                float4* dst4 = (float4*)&uout[((b * 8 + c) * S_ + h0 + ho) * S_ + wr * 8];
                dst4[0] = make_float4(xo[m][0], xo[m][1], xo[m][2], xo[m][3]);
                dst4[1] = make_float4(xo[m][4], xo[m][5], xo[m][6], xo[m][7]);
            }
        } else {
            // park xo -> B
            #pragma unroll
            for (int m = 0; m < 2; ++m) {
                const int run = tid + 512 * m;
                const int r = run & 63, w0 = (run >> 6) * 8;
                #pragma unroll
                for (int i = 0; i < 8; ++i) sP[OFF_B + r * RS + w0 + i] = xo[m][i];
            }
            __syncthreads();
            // mix: read B, write A
            {
                float M[64];
                #pragma unroll
                for (int i = 0; i < 64; ++i) M[i] = cm[i];
                #pragma unroll
                for (int m = 0; m < 2; ++m) {
                    const int p = tid + 512 * m;
                    const int ho = p >> 7, w = p & 127;
                    float v[8], o[8];
                    #pragma unroll
                    for (int c = 0; c < 8; ++c) v[c] = sP[OFF_B + (c * 8 + ho) * RS + w];
                    #pragma unroll
                    for (int dd = 0; dd < 8; ++dd) {
                        float a = 0.f;
                        #pragma unroll
                        for (int c = 0; c < 8; ++c) a = fmaf(M[dd * 8 + c], v[c], a);
                        o[dd] = a;
                    }
                    #pragma unroll
                    for (int c = 0; c < 8; ++c) sP[OFF_A + (c * 8 + ho) * RS + w] = o[c];
                }
            }
            __syncthreads();
            // X2: reg-cached coeffs; result -> U + publish edge rows
            const int wslot = k & 1;
            #pragma unroll
            for (int m = 0; m < 2; ++m) {
                const int run = tid + 512 * m;
                const int r = run & 63, wr = run >> 6;
                const int w0 = wr * 8;
                const int c = r >> 3, ho = r & 7;
                float e[12];
                #pragma unroll
                for (int j = 0; j < 12; ++j) {
                    const int wj = w0 - 2 + j;
                    const bool win = (wj >= 0 && wj < S_);
                    const float dv = win ? sP[OFF_A + r * RS + wj] : 0.f;
                    e[j] = rbk[m][j] * dv;
                }
                float o[8]; jrunN<12>(e, gk[m], o);
                #pragma unroll
                for (int i = 0; i < 8; ++i) sP[OFF_U + r * RS + w0 + i] = o[i];
                if (ho < 2 || ho >= 6) {
                    const int e_ = (ho < 2) ? ho : ho - 4;
                    float* hp = &halo[(wslot * NBLK + blk) * 4096 + (e_ * 8 + c) * 128 + w0];
                    #pragma unroll
                    for (int i = 0; i < 8; ++i)
                        __hip_atomic_store(&hp[i], o[i], __ATOMIC_RELAXED,
                                           __HIP_MEMORY_SCOPE_AGENT);
                }
            }
            __syncthreads();   // drains vmcnt: halo stores complete before flag
            if (tid == 0)
                __hip_atomic_store(&flags[blk], (unsigned)(k + 1), __ATOMIC_RELAXED,
                                   __HIP_MEMORY_SCOPE_AGENT);
        }
    }
}

extern "C" void kernel_launch(void* const* d_in, const int* in_sizes, int n_in,
                              void* d_out, int out_size, void* d_ws, size_t ws_size,
                              hipStream_t stream) {
    const float* u_in = (const float*)d_in[0];
    const float* ab   = (const float*)d_in[1];
    const float* bbta = (const float*)d_in[2];
    const float* atc  = (const float*)d_in[3];
    const float* btc  = (const float*)d_in[4];
    const float* cm   = (const float*)d_in[5];
    float* uo = (float*)d_out;

    __half2*  cf    = (__half2*)d_ws;                            // 10.5 MB
    float*    haloB = (float*)((char*)d_ws + (12u << 20));       // 8.4 MB
    unsigned* flags = (unsigned*)((char*)d_ws + (21u << 20));    // 1 KB (harness memsets ws -> 0)

    coef_kernel<<<dim3(512), dim3(256), 0, stream>>>(ab, atc, bbta, btc, cf);
    adi10_kernel<<<dim3(NBLK), dim3(512), 0, stream>>>(u_in, uo, cf, cm, haloB, flags);
}

// Round 11
// 152.675 us; speedup vs baseline: 1.6232x; 1.6232x over previous
//
#include <hip/hip_runtime.h>
#include <hip/hip_fp16.h>

// ADI diffusion B=16, C=8, S=128, 10 steps. Round 20: swizzled-LDS steps.
// r10 post-mortem: per-4B agent atomics -> 303MB WRITE_SIZE (no coalescing)
// => all in-kernel cross-block sync abandoned; multi-dispatch r9 (166.5us)
// is the base. w(step)~8us is LDS-ISSUE bound (~160 scalar b32 ops/thread).
// Steps now use 64x128 regions with block-XOR swizzle
//   word = r*128 + ((b ^ (r&31))<<2) + (w&3)
// -> X1/X2 taps = 4x ds_read_b128, park = 2x b128, coeff stage = b128,
// Y writes = b64 pairs; all patterns <=2-way banked. Edge runs use
// wave-uniform branches + reg zeros (same semantics as the old predicates).
// Head + coef kernels are byte-identical to round 9 (proven).

constexpr int S_  = 128;
constexpr int RS  = 129;            // head (unswizzled) LDS row stride
constexpr float EPSF = 1e-6f;
constexpr int CSS = 8 * 128 * 128;  // points per coeff field

// step-kernel swizzled LDS: 3 regions x 64 rows x 128 floats = 96 KB
constexpr int SOFF_A = 0;
constexpr int SOFF_B = 64 * 128;
constexpr int SOFF_C = 128 * 128;
constexpr int SPOOL  = 192 * 128;

__device__ __forceinline__ int swad(int r, int b) {
    return r * 128 + (((b) ^ (r & 31)) << 2);
}

template <int N>
__device__ __forceinline__ void jrunN(const float (&e)[N], const float (&g)[N],
                                      float (&o)[N - 4]) {
    // Jacobi-2 == fixed 5-point formula, stencil radius 2 per output.
    float x1[N];
    #pragma unroll
    for (int i = 1; i <= N - 2; ++i) x1[i] = fmaf(g[i], e[i - 1] + e[i + 1], e[i]);
    #pragma unroll
    for (int i = 2; i <= N - 3; ++i) o[i - 2] = fmaf(g[i], x1[i - 1] + x1[i + 1], e[i]);
}

// ---- coefficient precompute (round-9, proven): fields 0..9 Y@t_y(k),
// 10..19 X@t_x(k), 20 X@t=0. Packed __half2{g = rb*co, rb-1}.
__global__ __launch_bounds__(256) void coef_kernel(
    const float* __restrict__ ab, const float* __restrict__ atc,
    const float* __restrict__ bb, const float* __restrict__ btc,
    __half2* __restrict__ cf)
{
    for (int gc = blockIdx.x * 256 + threadIdx.x; gc < CSS; gc += gridDim.x * 256) {
        const int w = gc & 127, h = (gc >> 7) & 127;
        const float abv = ab[gc], atv = atc[gc], bbv = bb[gc], btv = btc[gc];
        const float nbY = (h == 0 || h == S_ - 1) ? 1.f : 2.f;
        const float nbX = (w == 0 || w == S_ - 1) ? 1.f : 2.f;
        for (int k = 0; k < 10; ++k) {
            const float ty = (2 * k + 1) * 0.0005f;
            const float tx = (2 * k + 2) * 0.0005f;
            float be = fminf(fmaxf(fmaf(btv, ty, bbv), EPSF), 10.f);
            float co = be * 0.001f;
            float rb = __builtin_amdgcn_rcpf(fmaf(nbY, co, 1.f) + EPSF);
            cf[k * CSS + gc] = __floats2half2_rn(rb * co, rb - 1.f);
            float al = fminf(fmaxf(fmaf(atv, tx, abv), EPSF), 10.f);
            co = al * 0.0005f;
            rb = __builtin_amdgcn_rcpf(fmaf(nbX, co, 1.f) + EPSF);
            cf[(10 + k) * CSS + gc] = __floats2half2_rn(rb * co, rb - 1.f);
        }
        float al = fminf(fmaxf(abv, EPSF), 10.f);
        float co = al * 0.0005f;
        float rb = __builtin_amdgcn_rcpf(fmaf(nbX, co, 1.f) + EPSF);
        cf[20 * CSS + gc] = __floats2half2_rn(rb * co, rb - 1.f);
    }
}

// ---- head kernel: byte-identical to round-9 step_kernel<true,false> ----
__global__ __launch_bounds__(512, 2) void head_kernel(
    const float* __restrict__ u0, __half* __restrict__ ud,
    const __half2* __restrict__ cfy, const __half2* __restrict__ cfx,
    const __half2* __restrict__ cfx0, const float* __restrict__ cm)
{
    constexpr int POOL   = 288 * RS;
    constexpr int OFF_A  = 0;
    constexpr int OFF_B  = 64 * RS;
    constexpr int OFF_CP = 192 * RS;
    constexpr int OFF_X0 = 96 * RS;
    __shared__ float sP[POOL];
    const int tid = threadIdx.x;
    const int b   = blockIdx.x >> 4;
    const int h0  = (blockIdx.x & 15) << 3;

    // stage 12-row pristine tile into ST=[0,96)
    #pragma unroll
    for (int m = 0; m < 2; ++m) {
        const int col = tid + 512 * m;
        const int c = col >> 7, w = col & 127;
        #pragma unroll
        for (int hh = 0; hh < 12; ++hh) {
            const int gh = h0 - 2 + hh;
            float v = 0.f;
            if (gh >= 0 && gh < S_) v = u0[((b * 8 + c) * S_ + gh) * S_ + w];
            sP[(c * 12 + hh) * RS + w] = v;
        }
    }
    // stage packed x@0 coeffs into [192,288)
    #pragma unroll
    for (int m = 0; m < 12; ++m) {
        const int task = tid + 512 * m;
        const int r = task >> 6, col2 = task & 63;
        const int c = r / 12, hh = r % 12;
        int gh = h0 - 2 + hh; gh = gh < 0 ? 0 : (gh >= S_ ? S_ - 1 : gh);
        const uint2 v = ((const uint2*)cfx0)[(c * S_ + gh) * 64 + col2];
        sP[OFF_CP + r * RS + col2 * 2]     = __uint_as_float(v.x);
        sP[OFF_CP + r * RS + col2 * 2 + 1] = __uint_as_float(v.y);
    }
    __syncthreads();
    {   // channel mix in place on ST
        float M[64];
        #pragma unroll
        for (int i = 0; i < 64; ++i) M[i] = cm[i];
        #pragma unroll
        for (int m = 0; m < 3; ++m) {
            const int p = tid + 512 * m;
            const int hh = p >> 7, w = p & 127;
            float v[8], o[8];
            #pragma unroll
            for (int c = 0; c < 8; ++c) v[c] = sP[(c * 12 + hh) * RS + w];
            #pragma unroll
            for (int dd = 0; dd < 8; ++dd) {
                float a = 0.f;
                #pragma unroll
                for (int c = 0; c < 8; ++c) a = fmaf(M[dd * 8 + c], v[c], a);
                o[dd] = a;
            }
            #pragma unroll
            for (int c = 0; c < 8; ++c) sP[(c * 12 + hh) * RS + w] = o[c];
        }
    }
    __syncthreads();
    // x@0: 96 rows x 16 runs, 3/thread -> X0
    #pragma unroll
    for (int m = 0; m < 3; ++m) {
        const int task = tid + 512 * m;
        const int r96 = task % 96, wr = task / 96;
        const int hh = r96 % 12;
        const int gh = h0 - 2 + hh;
        const bool rowin = (gh >= 0 && gh < S_);
        const int w0 = wr * 8;
        float e[12], g[12];
        #pragma unroll
        for (int j = 0; j < 12; ++j) {
            const int wj = w0 - 2 + j;
            const bool win = (wj >= 0 && wj < S_);
            const float dv = win ? sP[r96 * RS + wj] : 0.f;
            uint cb = (rowin && win) ? __float_as_uint(sP[OFF_CP + r96 * RS + wj]) : 0u;
            const float2 f = __half22float2(*reinterpret_cast<__half2*>(&cb));
            e[j] = (1.f + f.y) * dv;
            g[j] = f.x;
        }
        float o[8]; jrunN<12>(e, g, o);
        #pragma unroll
        for (int i = 0; i < 8; ++i) sP[OFF_X0 + r96 * RS + w0 + i] = o[i];
    }
    __syncthreads();

    // Y stage: reads X0; 12-in -> 8-out -> A
    #pragma unroll
    for (int m = 0; m < 2; ++m) {
        const int col = tid + 512 * m;
        const int c = col >> 7, w = col & 127;
        float e[12], g[12];
        #pragma unroll
        for (int hh = 0; hh < 12; ++hh) {
            const int gh = h0 - 2 + hh;
            const bool inr = (gh >= 0 && gh < S_);
            const int ghc = inr ? gh : 0;
            const float dv = sP[OFF_X0 + (c * 12 + hh) * RS + w];
            const float2 f = __half22float2(cfy[(c * S_ + ghc) * S_ + w]);
            e[hh] = (1.f + f.y) * dv;
            g[hh] = inr ? f.x : 0.f;
        }
        float o[8]; jrunN<12>(e, g, o);
        #pragma unroll
        for (int i = 0; i < 8; ++i) sP[OFF_A + (c * 8 + i) * RS + w] = o[i];
    }
    __syncthreads();   // CP (x-coeff) overwrite below aliases X0 region reads? no; keep for safety
    // stage packed x-coeff into CP rows [0,64) of CP region
    #pragma unroll
    for (int m = 0; m < 8; ++m) {
        const int task = tid + 512 * m;
        const int r = task >> 6, col2 = task & 63;
        const int c = r >> 3, ho = r & 7;
        const uint2 v = ((const uint2*)cfx)[(c * S_ + h0 + ho) * 64 + col2];
        sP[OFF_CP + r * RS + col2 * 2]     = __uint_as_float(v.x);
        sP[OFF_CP + r * RS + col2 * 2 + 1] = __uint_as_float(v.y);
    }
    __syncthreads();

    // X1: 64 rows x 16 runs, 2/thread; cache rb/g for X2
    float rbk[2][12], gk[2][12], xo[2][8];
    #pragma unroll
    for (int m = 0; m < 2; ++m) {
        const int run = tid + 512 * m;
        const int r = run & 63, wr = run >> 6;
        const int w0 = wr * 8;
        float e[12];
        #pragma unroll
        for (int j = 0; j < 12; ++j) {
            const int wj = w0 - 2 + j;
            const bool win = (wj >= 0 && wj < S_);
            const float dv = win ? sP[OFF_A + r * RS + wj] : 0.f;
            uint cb = win ? __float_as_uint(sP[OFF_CP + r * RS + wj]) : 0u;
            const float2 f = __half22float2(*reinterpret_cast<__half2*>(&cb));
            rbk[m][j] = 1.f + f.y; gk[m][j] = f.x;
            e[j] = rbk[m][j] * dv;
        }
        jrunN<12>(e, gk[m], xo[m]);
    }
    // park xo -> B
    #pragma unroll
    for (int m = 0; m < 2; ++m) {
        const int run = tid + 512 * m;
        const int r = run & 63, w0 = (run >> 6) * 8;
        #pragma unroll
        for (int i = 0; i < 8; ++i) sP[OFF_B + r * RS + w0 + i] = xo[m][i];
    }
    __syncthreads();
    {   // mix: read B, write A
        float M[64];
        #pragma unroll
        for (int i = 0; i < 64; ++i) M[i] = cm[i];
        #pragma unroll
        for (int m = 0; m < 2; ++m) {
            const int p = tid + 512 * m;
            const int ho = p >> 7, w = p & 127;
            float v[8], o[8];
            #pragma unroll
            for (int c = 0; c < 8; ++c) v[c] = sP[OFF_B + (c * 8 + ho) * RS + w];
            #pragma unroll
            for (int dd = 0; dd < 8; ++dd) {
                float a = 0.f;
                #pragma unroll
                for (int c = 0; c < 8; ++c) a = fmaf(M[dd * 8 + c], v[c], a);
                o[dd] = a;
            }
            #pragma unroll
            for (int c = 0; c < 8; ++c) sP[OFF_A + (c * 8 + ho) * RS + w] = o[c];
        }
    }
    __syncthreads();
    // X2 -> fp16 out
    #pragma unroll
    for (int m = 0; m < 2; ++m) {
        const int run = tid + 512 * m;
        const int r = run & 63, wr = run >> 6;
        const int w0 = wr * 8;
        const int c = r >> 3, ho = r & 7;
        float e[12];
        #pragma unroll
        for (int j = 0; j < 12; ++j) {
            const int wj = w0 - 2 + j;
            const bool win = (wj >= 0 && wj < S_);
            const float dv = win ? sP[OFF_A + r * RS + wj] : 0.f;
            e[j] = rbk[m][j] * dv;
        }
        float o[8]; jrunN<12>(e, gk[m], o);
        __half2* d2 = (__half2*)&ud[((b * 8 + c) * S_ + h0 + ho) * S_ + w0];
        d2[0] = __floats2half2_rn(o[0], o[1]);
        d2[1] = __floats2half2_rn(o[2], o[3]);
        d2[2] = __floats2half2_rn(o[4], o[5]);
        d2[3] = __floats2half2_rn(o[6], o[7]);
    }
}

// ---- mid/last step: swizzled LDS, vectorized ----
template <bool LASTK>
__global__ __launch_bounds__(512) void stepS_kernel(
    const __half* __restrict__ us, void* __restrict__ udst_,
    const __half2* __restrict__ cfy, const __half2* __restrict__ cfx,
    const float* __restrict__ cm)
{
    __shared__ __align__(16) float sP[SPOOL];
    const int tid = threadIdx.x;
    const int b   = blockIdx.x >> 4;
    const int h0  = (blockIdx.x & 15) << 3;

    // ---- Y: 512 col-pairs (c, w=2wp/2wp+1); 12-in -> 8-out -> A (swz)
    {
        const int c  = tid >> 6;
        const int wp = tid & 63;
        const int wbase = 2 * wp;
        uint du[12]; uint2 dc[12];
        #pragma unroll
        for (int hh = 0; hh < 12; ++hh) {
            const int gh = h0 - 2 + hh;
            const bool inr = (gh >= 0 && gh < S_);
            const int ghc = inr ? gh : 0;
            du[hh] = inr ? *(const uint*)&us[((b * 8 + c) * S_ + ghc) * S_ + wbase] : 0u;
            dc[hh] = *(const uint2*)&cfy[(c * S_ + ghc) * S_ + wbase];
        }
        float o2[2][8];
        #pragma unroll
        for (int s = 0; s < 2; ++s) {
            float e[12], g[12];
            #pragma unroll
            for (int hh = 0; hh < 12; ++hh) {
                const int gh = h0 - 2 + hh;
                const bool inr = (gh >= 0 && gh < S_);
                uint ub = du[hh];
                __half2 hu = *reinterpret_cast<__half2*>(&ub);
                const float dv = s ? __high2float(hu) : __low2float(hu);
                uint cb = s ? dc[hh].y : dc[hh].x;
                const float2 f = __half22float2(*reinterpret_cast<__half2*>(&cb));
                e[hh] = (1.f + f.y) * dv;
                g[hh] = inr ? f.x : 0.f;
            }
            jrunN<12>(e, g, o2[s]);
        }
        #pragma unroll
        for (int i = 0; i < 8; ++i) {
            const int r = c * 8 + i;
            float2* p = (float2*)&sP[SOFF_A + r * 128 +
                                     (((wp >> 1) ^ (r & 31)) << 2) + 2 * (wp & 1)];
            *p = make_float2(o2[0][i], o2[1][i]);
        }
    }
    // ---- C stage: 2048 tasks (64 rows x 32 col4), 4/thread, uint4 -> b128
    {
        const uint* cfxu = (const uint*)cfx;
        #pragma unroll
        for (int m = 0; m < 4; ++m) {
            const int task = tid + 512 * m;
            const int r = task >> 5, col4 = task & 31;
            const int c = r >> 3, ho = r & 7;
            const uint4 v = *(const uint4*)&cfxu[(c * S_ + h0 + ho) * S_ + col4 * 4];
            *(float4*)&sP[SOFF_C + swad(r, col4)] =
                make_float4(__uint_as_float(v.x), __uint_as_float(v.y),
                            __uint_as_float(v.z), __uint_as_float(v.w));
        }
    }
    __syncthreads();

    // ---- X1: 1024 runs, 2/thread; 4x b128 taps from A and C
    float rbk[2][12], gk[2][12], xo[2][8];
    #pragma unroll
    for (int m = 0; m < 2; ++m) {
        const int r  = tid & 63;
        const int wr = (tid >> 6) + 8 * m;      // wave-uniform
        const int w0 = wr * 8;
        float f[16]; uint cb[16];
        #pragma unroll
        for (int i = 0; i < 4; ++i) {
            const int bb = (w0 >> 2) - 1 + i;
            if (bb >= 0 && bb < 32) {           // wave-uniform branch
                const float4 va = *(const float4*)&sP[SOFF_A + swad(r, bb)];
                const float4 vc = *(const float4*)&sP[SOFF_C + swad(r, bb)];
                f[4 * i + 0] = va.x; f[4 * i + 1] = va.y;
                f[4 * i + 2] = va.z; f[4 * i + 3] = va.w;
                cb[4 * i + 0] = __float_as_uint(vc.x);
                cb[4 * i + 1] = __float_as_uint(vc.y);
                cb[4 * i + 2] = __float_as_uint(vc.z);
                cb[4 * i + 3] = __float_as_uint(vc.w);
            } else {
                f[4 * i + 0] = f[4 * i + 1] = f[4 * i + 2] = f[4 * i + 3] = 0.f;
                cb[4 * i + 0] = cb[4 * i + 1] = cb[4 * i + 2] = cb[4 * i + 3] = 0u;
            }
        }
        float e[12];
        #pragma unroll
        for (int j = 0; j < 12; ++j) {
            uint c_ = cb[j + 2];
            const float2 fc = __half22float2(*reinterpret_cast<__half2*>(&c_));
            rbk[m][j] = 1.f + fc.y; gk[m][j] = fc.x;
            e[j] = rbk[m][j] * f[j + 2];
        }
        jrunN<12>(e, gk[m], xo[m]);
    }

    if (LASTK) {
        // final step: no mix; xo -> fp32 d_out
        float* ud = (float*)udst_;
        #pragma unroll
        for (int m = 0; m < 2; ++m) {
            const int r  = tid & 63;
            const int wr = (tid >> 6) + 8 * m;
            const int c = r >> 3, ho = r & 7;
            float4* dst4 = (float4*)&ud[((b * 8 + c) * S_ + h0 + ho) * S_ + wr * 8];
            dst4[0] = make_float4(xo[m][0], xo[m][1], xo[m][2], xo[m][3]);
            dst4[1] = make_float4(xo[m][4], xo[m][5], xo[m][6], xo[m][7]);
        }
    } else {
        // park xo -> B as 2x b128
        #pragma unroll
        for (int m = 0; m < 2; ++m) {
            const int r  = tid & 63;
            const int wr = (tid >> 6) + 8 * m;
            *(float4*)&sP[SOFF_B + swad(r, 2 * wr)] =
                make_float4(xo[m][0], xo[m][1], xo[m][2], xo[m][3]);
            *(float4*)&sP[SOFF_B + swad(r, 2 * wr + 1)] =
                make_float4(xo[m][4], xo[m][5], xo[m][6], xo[m][7]);
        }
        __syncthreads();
        {   // mix: 1024 pts, 2/thread; read B, write A (swz b32, conflict-free)
            float M[64];
            #pragma unroll
            for (int i = 0; i < 64; ++i) M[i] = cm[i];
            #pragma unroll
            for (int m = 0; m < 2; ++m) {
                const int p = tid + 512 * m;
                const int ho = p >> 7, w = p & 127;
                float v[8], o[8];
                #pragma unroll
                for (int c = 0; c < 8; ++c) {
                    const int r = c * 8 + ho;
                    v[c] = sP[SOFF_B + r * 128 + (((w >> 2) ^ (r & 31)) << 2) + (w & 3)];
                }
                #pragma unroll
                for (int dd = 0; dd < 8; ++dd) {
                    float a = 0.f;
                    #pragma unroll
                    for (int c = 0; c < 8; ++c) a = fmaf(M[dd * 8 + c], v[c], a);
                    o[dd] = a;
                }
                #pragma unroll
                for (int c = 0; c < 8; ++c) {
                    const int r = c * 8 + ho;
                    sP[SOFF_A + r * 128 + (((w >> 2) ^ (r & 31)) << 2) + (w & 3)] = o[c];
                }
            }
        }
        __syncthreads();
        // X2: re-read A (4x b128), reg-cached coeffs -> fp16 out (one b128 store)
        __half* ud = (__half*)udst_;
        #pragma unroll
        for (int m = 0; m < 2; ++m) {
            const int r  = tid & 63;
            const int wr = (tid >> 6) + 8 * m;
            const int w0 = wr * 8;
            const int c = r >> 3, ho = r & 7;
            float f[16];
            #pragma unroll
            for (int i = 0; i < 4; ++i) {
                const int bb = (w0 >> 2) - 1 + i;
                if (bb >= 0 && bb < 32) {
                    const float4 va = *(const float4*)&sP[SOFF_A + swad(r, bb)];
                    f[4 * i + 0] = va.x; f[4 * i + 1] = va.y;
                    f[4 * i + 2] = va.z; f[4 * i + 3] = va.w;
                } else {
                    f[4 * i + 0] = f[4 * i + 1] = f[4 * i + 2] = f[4 * i + 3] = 0.f;
                }
            }
            float e[12];
            #pragma unroll
            for (int j = 0; j < 12; ++j) e[j] = rbk[m][j] * f[j + 2];
            float o[8]; jrunN<12>(e, gk[m], o);
            __half2 q0 = __floats2half2_rn(o[0], o[1]);
            __half2 q1 = __floats2half2_rn(o[2], o[3]);
            __half2 q2 = __floats2half2_rn(o[4], o[5]);
            __half2 q3 = __floats2half2_rn(o[6], o[7]);
            uint4 pk;
            pk.x = *reinterpret_cast<uint*>(&q0);
            pk.y = *reinterpret_cast<uint*>(&q1);
            pk.z = *reinterpret_cast<uint*>(&q2);
            pk.w = *reinterpret_cast<uint*>(&q3);
            *(uint4*)&ud[((b * 8 + c) * S_ + h0 + ho) * S_ + w0] = pk;
        }
    }
}

extern "C" void kernel_launch(void* const* d_in, const int* in_sizes, int n_in,
                              void* d_out, int out_size, void* d_ws, size_t ws_size,
                              hipStream_t stream) {
    const float* u_in = (const float*)d_in[0];
    const float* ab   = (const float*)d_in[1];
    const float* bbta = (const float*)d_in[2];
    const float* atc  = (const float*)d_in[3];
    const float* btc  = (const float*)d_in[4];
    const float* cm   = (const float*)d_in[5];
    float* uo = (float*)d_out;
    __half*  h1 = (__half*)d_ws;                                   // 4.2MB
    __half*  h2 = (__half*)((char*)d_ws + (8u << 20));             // 4.2MB
    __half2* cf = (__half2*)((char*)d_ws + (16u << 20));           // 11MB

    coef_kernel<<<dim3(512), dim3(256), 0, stream>>>(ab, atc, bbta, btc, cf);

    const dim3 g(256), blk(512);
    head_kernel<<<g, blk, 0, stream>>>(u_in, h1, cf + 0 * CSS, cf + 10 * CSS,
                                       cf + 20 * CSS, cm);
    const __half* s = h1; __half* d = h2;
    for (int k = 1; k <= 8; ++k) {
        stepS_kernel<false><<<g, blk, 0, stream>>>(s, d, cf + k * CSS,
                                                   cf + (10 + k) * CSS, cm);
        const __half* ns = d;
        d = (d == h2) ? h1 : h2;
        s = ns;
    }
    stepS_kernel<true><<<g, blk, 0, stream>>>(s, uo, cf + 9 * CSS,
                                              cf + 19 * CSS, cm);
}